// Round 1
// baseline (228.190 us; speedup 1.0000x reference)
//
#include <hip/hip_runtime.h>
#include <hip/hip_bf16.h>

// FANS neural output update:
//   x = concat(x_f, x_b)            (B, 32) fp32
//   z = x[:, sel_idx]               (B, 64, 8)
//   h = tanh(z @ W1 + b1)           (B, 64, 32)
//   y = h @ W2 + b2                 (B, 64)
//
// Layout: lane = row, group g wave-uniform -> all weight reads are scalar
// (SMEM) loads; x rows staged in LDS (stride 33, conflict-free gather);
// y staged in LDS (stride 65) for fully coalesced global stores.

#define B_TOTAL 65536
#define NGRP    64
#define KSEL    8
#define NH      32

__global__ __launch_bounds__(256, 4) void fans_fwd(
    const float* __restrict__ xf, const float* __restrict__ xb,
    const int*   __restrict__ sel,
    const float* __restrict__ W1, const float* __restrict__ b1,
    const float* __restrict__ W2, const float* __restrict__ b2,
    float* __restrict__ out)
{
    __shared__ float xs[64 * 33];   // 64 rows x 32 cols, padded (+1)
    __shared__ float ys[64 * 65];   // 64 rows x 64 groups, padded (+1)

    const int tid  = threadIdx.x;        // 0..255
    const int lane = tid & 63;           // row within block tile
    const int wav  = tid >> 6;           // 0..3
    const int row0 = blockIdx.x * 64;

    // Stage 64 rows of x = concat(xf, xb) into LDS. Consecutive tid ->
    // consecutive c, so the 16-wide xf / xb segments are coalesced.
    #pragma unroll
    for (int i = tid; i < 64 * 32; i += 256) {
        const int r = i >> 5, c = i & 31;
        const float v = (c < 16) ? xf[(row0 + r) * 16 + c]
                                 : xb[(row0 + r) * 16 + (c - 16)];
        xs[r * 33 + c] = v;
    }
    __syncthreads();

    const float* xrow = &xs[lane * 33];

    // Each wave handles 16 groups for its 64 rows (one row per lane).
    for (int gi = 0; gi < 16; ++gi) {
        const int g = wav * 16 + gi;     // wave-uniform

        // Gather selected inputs: column index is wave-uniform, address
        // lane*33 + c -> bank (lane + c) % 32 -> conflict-free.
        float z[KSEL];
        #pragma unroll
        for (int k = 0; k < KSEL; ++k)
            z[k] = xrow[sel[g * KSEL + k]];

        const float* __restrict__ w1g = &W1[g * KSEL * NH];
        const float* __restrict__ b1g = &b1[g * NH];
        const float* __restrict__ w2g = &W2[g * NH];

        float acc[NH];
        #pragma unroll
        for (int h = 0; h < NH; ++h) acc[h] = b1g[h];

        // k-outer / h-inner: w1 addresses sequential -> s_load_dwordx16
        // friendly; weight operand is a single SGPR per v_fmac.
        #pragma unroll
        for (int k = 0; k < KSEL; ++k) {
            const float zk = z[k];
            #pragma unroll
            for (int h = 0; h < NH; ++h)
                acc[h] = fmaf(zk, w1g[k * NH + h], acc[h]);
        }

        float y = b2[g];
        #pragma unroll
        for (int h = 0; h < NH; ++h) {
            // tanh(a) = 1 - 2/(exp(2a)+1), native v_exp_f32 path
            const float e = __expf(2.0f * acc[h]);
            const float t = 1.0f - 2.0f / (e + 1.0f);
            y = fmaf(t, w2g[h], y);
        }

        // bank (lane + g) % 32 -> conflict-free
        ys[lane * 65 + g] = y;
    }
    __syncthreads();

    // Coalesced write-out: 64 rows x 64 groups per block.
    #pragma unroll
    for (int i = tid; i < 64 * 64; i += 256) {
        const int r = i >> 6, c = i & 63;
        out[(row0 + r) * 64 + c] = ys[r * 65 + c];
    }
}

extern "C" void kernel_launch(void* const* d_in, const int* in_sizes, int n_in,
                              void* d_out, int out_size, void* d_ws, size_t ws_size,
                              hipStream_t stream) {
    const float* xf = (const float*)d_in[0];
    const float* xb = (const float*)d_in[1];
    const int*   sel = (const int*)d_in[2];
    const float* W1 = (const float*)d_in[3];
    const float* b1 = (const float*)d_in[4];
    const float* W2 = (const float*)d_in[5];
    const float* b2 = (const float*)d_in[6];
    float* out = (float*)d_out;

    dim3 grid(B_TOTAL / 64), block(256);
    hipLaunchKernelGGL(fans_fwd, grid, block, 0, stream,
                       xf, xb, sel, W1, b1, W2, b2, out);
}